// Round 12
// baseline (779.069 us; speedup 1.0000x reference)
//
#include <hip/hip_runtime.h>
#include <hip/hip_fp16.h>

// ---------------------------------------------------------------------------
// R12: persistent-kernel HYBRID. One kernel, 1024 blocks x 256 thr, running
// R10's per-layer code (h activations in GLOBAL f16 column-planes, NT I/O,
// LDS stat replicas -> 64 padded global slots -> per-block prologue reduce),
// with the 11 kernel boundaries replaced by a lean device barrier:
//   deposit (device atomicAdd) -> RELEASE arrival on 8 padded counters ->
//   block 0 polls relaxed, publishes 8 padded flags (RELEASE) ->
//   others spin RELAXED on one read-only flag line + one final ACQUIRE.
// Why: R10 showed ~20us per kernel boundary (launch+drain+cache inv) x 11.
// R1-R4's persistent failure was register spills (acts in registers), NOT
// the barrier; here per-thread live state is ~80 VGPR by construction.
// Co-residency: launch_bounds(256,4) -> 4 blocks/CU x 256 CU = 1024 ✓
// (R1-R4 ran this shape at 49% occupancy without deadlock).
// ---------------------------------------------------------------------------

#define NBLK 1024
#define NTHR 256
#define BATCHN 1048576
#define NREP 32        // LDS stat replicas (stride 49 odd -> bank bijection)
#define SSTR 49
#define NSLOT 64       // global stat slots
#define SLOTW 48       // floats per slot: [0..23]=sum, [24..47]=sumsq
#define BARPAD 32      // uints per barrier/flag line (128B)

static_assert(NBLK * NTHR * 4 == BATCHN, "row coverage");

static constexpr int D_[12] = {64, 4, 20, 10, 10, 10, 10, 10, 5, 5, 5, 1};

typedef float floatx4 __attribute__((ext_vector_type(4)));

static constexpr int np_(int d) { return (d + 1) / 2; }
static constexpr int w2offc(int l) {   // float2 offset of layer l (l>=1)
    int o = 0;
    for (int k = 1; k < l; ++k) o += D_[k + 1] * np_(D_[k]);
    return o;
}
static constexpr int boffc(int l) {
    int o = 0;
    for (int k = 0; k < l; ++k) o += D_[k + 1];
    return o;
}
static constexpr int W2TOT = w2offc(11);   // 398 float2
static constexpr int BTOT = boffc(11);     // 90
static constexpr int GTOT = boffc(10);     // 89

__device__ __forceinline__ float fast_tanh(float x) {
    const float e = exp2f(x * 2.8853900817779268f);
    return 1.0f - __fdividef(2.0f, e + 1.0f);
}
__device__ __forceinline__ floatx4 ntld4(const void* p) {
    return __builtin_nontemporal_load((const floatx4*)p);
}
__device__ __forceinline__ void ntst4(void* p, floatx4 v) {
    __builtin_nontemporal_store(v, (floatx4*)p);
}

struct Params {
    const float* x;
    const float* W[11];
    const float* b[11];
    const float* g[10];
    const float* bt[10];
    float* out;
    float* gstats;   // [10][NSLOT][SLOTW]
    unsigned* bar;   // [10][8][BARPAD]
    unsigned* flags; // [10][8][BARPAD]
    __half2* hA;     // <=5 planes
    __half2* hB;     // <=10 planes
};

// ---- device barrier (layer L), lean: relaxed spin + single final acquire ---
__device__ __forceinline__ void dev_barrier(const Params& p, int L, int tid, int bid) {
    __syncthreads();   // all waves' stores drained (vmcnt0 at barrier)
    if (tid == 0) {
        unsigned* bar = p.bar + (size_t)L * 8 * BARPAD;
        unsigned* flg = p.flags + (size_t)L * 8 * BARPAD;
        const int slot = bid & 7;
        __hip_atomic_fetch_add(&bar[slot * BARPAD], 1u,
                               __ATOMIC_RELEASE, __HIP_MEMORY_SCOPE_AGENT);
        if (bid == 0) {
            unsigned tot;
            do {
                tot = 0;
                for (int q = 0; q < 8; ++q)
                    tot += __hip_atomic_load(&bar[q * BARPAD],
                                             __ATOMIC_RELAXED, __HIP_MEMORY_SCOPE_AGENT);
                if (tot < NBLK) __builtin_amdgcn_s_sleep(2);
            } while (tot < NBLK);
            (void)__hip_atomic_load(&bar[0], __ATOMIC_ACQUIRE,
                                    __HIP_MEMORY_SCOPE_AGENT);
            for (int q = 0; q < 8; ++q)
                __hip_atomic_store(&flg[q * BARPAD], 1u,
                                   __ATOMIC_RELEASE, __HIP_MEMORY_SCOPE_AGENT);
        } else {
            while (__hip_atomic_load(&flg[slot * BARPAD],
                                     __ATOMIC_RELAXED, __HIP_MEMORY_SCOPE_AGENT) == 0u)
                __builtin_amdgcn_s_sleep(2);
            (void)__hip_atomic_load(&flg[slot * BARPAD],
                                    __ATOMIC_ACQUIRE, __HIP_MEMORY_SCOPE_AGENT);
        }
    }
    __syncthreads();
}

// ---- block-end stats deposit -----------------------------------------------
template <int DOUT>
__device__ __forceinline__ void stats_deposit(float* bsum, float* __restrict__ gslots,
                                              int tid, int bid) {
    __syncthreads();
    if (tid < 2 * DOUT) {
        const int idx = (tid < DOUT) ? tid : (24 + (tid - DOUT));
        float v = 0.0f;
        for (int r = 0; r < NREP; ++r) v += bsum[r * SSTR + idx];
        atomicAdd(&gslots[(bid & (NSLOT - 1)) * SLOTW + idx], v);   // device scope
    }
}

// ---- per-layer: prologue reduce + BN+tanh + linear + stats -----------------
template <int L>
__device__ __forceinline__ void do_layer(const Params& p,
                                         const __half2* __restrict__ hin,
                                         __half2* __restrict__ hout,
                                         const float2* lw2, const float* lB,
                                         const float* lG, const float* lT,
                                         float* bsum, float* red,
                                         float* lsc, float* lsh,
                                         int tid, int bid) {
    constexpr int DIN = D_[L], DOUT = D_[L + 1];
    constexpr int NPI = np_(DIN), NPO = np_(DOUT);
    constexpr int WO = w2offc(L), BO = boffc(L), GO = boffc(L - 1);
    const float* gsPrev = p.gstats + (size_t)(L - 1) * NSLOT * SLOTW;
    float* gsOut = p.gstats + (size_t)L * NSLOT * SLOTW;

    // zero bsum + red (previous uses finished: barrier's trailing sync)
    for (int i = tid; i < NREP * SSTR; i += NTHR) bsum[i] = 0.0f;
    if (tid < 2 * DIN) red[tid] = 0.0f;
    __syncthreads();

    // prologue: reduce prev layer's 64 slots (plain loads; post-acquire)
    {
        const int f = tid & 63, c = tid >> 6;   // c in 0..3
        if (f < 2 * DIN) {
            const int idx = (f < DIN) ? f : (24 + (f - DIN));
            float v = 0.0f;
#pragma unroll
            for (int q = 0; q < 16; ++q)
                v += gsPrev[(c * 16 + q) * SLOTW + idx];
            atomicAdd(&red[f], v);
        }
    }
    __syncthreads();
    if (tid < DIN) {
        constexpr float inv = 1.0f / (float)BATCHN;
        const float m = red[tid] * inv;
        const float var = fmaxf(red[DIN + tid] * inv - m * m, 0.0f);
        const float sc = lG[GO + tid] * rsqrtf(var + 1e-5f);
        lsc[tid] = sc;
        lsh[tid] = lT[GO + tid] - m * sc;
    }
    __syncthreads();

    const int ei = bid * NTHR + tid;   // 4-row group

    __half2 a2[4][NPI];
#pragma unroll
    for (int cp = 0; cp < NPI; ++cp) {
        const floatx4 pl = ntld4((const float*)(hin + (size_t)cp * BATCHN) + (size_t)ei * 4);
        const __half2* h4 = (const __half2*)&pl;
#pragma unroll
        for (int r = 0; r < 4; ++r) {
            const float t0 = fast_tanh(fmaf(__low2float(h4[r]), lsc[2 * cp], lsh[2 * cp]));
            const float t1 = (2 * cp + 1 < DIN)
                ? fast_tanh(fmaf(__high2float(h4[r]), lsc[2 * cp + 1], lsh[2 * cp + 1]))
                : 0.0f;
            a2[r][cp] = __floats2half2_rn(t0, t1);
        }
    }

    const int rep = (tid & 31) * SSTR;
#pragma unroll
    for (int op = 0; op < NPO; ++op) {
        const int o0 = 2 * op, o1 = o0 + 1;
        float a0[4], a1[4];
#pragma unroll
        for (int r = 0; r < 4; ++r) {
            a0[r] = lB[BO + o0];
            a1[r] = (o1 < DOUT) ? lB[BO + o1] : 0.0f;
        }
#pragma unroll
        for (int cp = 0; cp < NPI; ++cp) {
            const float2 w0 = lw2[WO + o0 * NPI + cp];
            const float2 w1 = (o1 < DOUT) ? lw2[WO + o1 * NPI + cp] : make_float2(0.f, 0.f);
#pragma unroll
            for (int r = 0; r < 4; ++r) {
                const float x0 = __low2float(a2[r][cp]);
                const float x1 = __high2float(a2[r][cp]);
                a0[r] = fmaf(w0.x, x0, fmaf(w0.y, x1, a0[r]));
                a1[r] = fmaf(w1.x, x0, fmaf(w1.y, x1, a1[r]));
            }
        }
        {
            const float s0 = (a0[0] + a0[1]) + (a0[2] + a0[3]);
            const float q0 = fmaf(a0[0], a0[0], fmaf(a0[1], a0[1],
                              fmaf(a0[2], a0[2], a0[3] * a0[3])));
            atomicAdd(&bsum[rep + o0], s0);
            atomicAdd(&bsum[rep + 24 + o0], q0);
            if (o1 < DOUT) {
                const float s1 = (a1[0] + a1[1]) + (a1[2] + a1[3]);
                const float q1 = fmaf(a1[0], a1[0], fmaf(a1[1], a1[1],
                                  fmaf(a1[2], a1[2], a1[3] * a1[3])));
                atomicAdd(&bsum[rep + o1], s1);
                atomicAdd(&bsum[rep + 24 + o1], q1);
            }
        }
        floatx4 st;
        __half2* sp = (__half2*)&st;
#pragma unroll
        for (int r = 0; r < 4; ++r)
            sp[r] = __floats2half2_rn(a0[r], (o1 < DOUT) ? a1[r] : 0.0f);
        ntst4((float*)(hout + (size_t)op * BATCHN) + (size_t)ei * 4, st);
    }
    stats_deposit<DOUT>(bsum, gsOut, tid, bid);
    dev_barrier(p, L, tid, bid);
}

// ---------------------------------------------------------------------------
__global__ void __launch_bounds__(NTHR, 4) mlp_fused(Params p) {
    __shared__ __align__(16) float lw0[256];
    __shared__ __align__(8) float2 lw2[W2TOT];
    __shared__ float lB[BTOT], lG[GTOT], lT[GTOT];
    __shared__ float bsum[NREP * SSTR];
    __shared__ float red[40], lsc[20], lsh[20];
    __shared__ __half2 hs[2][1024];

    const int tid = threadIdx.x, bid = blockIdx.x;

    // ---- stage all weights once ----
    lw0[tid] = p.W[0][tid];
    for (int i = tid; i < W2TOT; i += NTHR) {
        // find layer for flat index i (constexpr-friendly small loop)
        int l = 1;
        while (l < 10 && i >= w2offc(l + 1)) ++l;
        const int DIN = D_[l], NPI = np_(DIN);
        const int li = i - w2offc(l);
        const int o = li / NPI, cp = li - o * NPI;
        const float w0 = p.W[l][o * DIN + 2 * cp];
        const float w1 = (2 * cp + 1 < DIN) ? p.W[l][o * DIN + 2 * cp + 1] : 0.0f;
        lw2[i] = make_float2(w0, w1);
    }
    for (int l = 0; l < 11; ++l)
        if (tid < D_[l + 1]) lB[boffc(l) + tid] = p.b[l][tid];
    for (int l = 0; l < 10; ++l)
        if (tid < D_[l + 1]) {
            lG[boffc(l) + tid] = p.g[l][tid];
            lT[boffc(l) + tid] = p.bt[l][tid];
        }
    for (int i = tid; i < NREP * SSTR; i += NTHR) bsum[i] = 0.0f;
    __syncthreads();

    // ---- layer 0: x(64) -> h0 (2 planes), 4 lanes/row, shfl reduce ----
    {
        const int wv = tid >> 6, lane = tid & 63, grp = lane >> 2, sub = lane & 3;
        floatx4 w[4][4];
        float bb[4];
#pragma unroll
        for (int o = 0; o < 4; ++o) {
            bb[o] = lB[boffc(0) + o];
#pragma unroll
            for (int q = 0; q < 4; ++q)
                w[o][q] = *(const floatx4*)&lw0[o * 64 + sub * 16 + q * 4];
        }
        float sl[4] = {0.f, 0.f, 0.f, 0.f}, ql[4] = {0.f, 0.f, 0.f, 0.f};

        const int rbase = bid * 1024;
#pragma unroll
        for (int pass = 0; pass < 16; ++pass) {
            const int lrow = wv * 16 + grp + pass * 64;
            const float* xr = p.x + (size_t)(rbase + lrow) * 64 + sub * 16;
            float par[4] = {0.f, 0.f, 0.f, 0.f};
#pragma unroll
            for (int q = 0; q < 4; ++q) {
                const floatx4 xv = ntld4(xr + q * 4);
#pragma unroll
                for (int o = 0; o < 4; ++o)
                    par[o] = fmaf(w[o][q].x, xv.x, fmaf(w[o][q].y, xv.y,
                              fmaf(w[o][q].z, xv.z, fmaf(w[o][q].w, xv.w, par[o]))));
            }
#pragma unroll
            for (int o = 0; o < 4; ++o) {
                par[o] += __shfl_xor(par[o], 1, 64);
                par[o] += __shfl_xor(par[o], 2, 64);
            }
            if (sub == 0) {
                float hv[4];
#pragma unroll
                for (int o = 0; o < 4; ++o) {
                    hv[o] = par[o] + bb[o];
                    sl[o] += hv[o];
                    ql[o] = fmaf(hv[o], hv[o], ql[o]);
                }
                hs[0][lrow] = __floats2half2_rn(hv[0], hv[1]);
                hs[1][lrow] = __floats2half2_rn(hv[2], hv[3]);
            }
        }
        if (sub == 0) {
            const int rep = (tid & 31) * SSTR;
#pragma unroll
            for (int o = 0; o < 4; ++o) {
                atomicAdd(&bsum[rep + o], sl[o]);
                atomicAdd(&bsum[rep + 24 + o], ql[o]);
            }
        }
        __syncthreads();
        ntst4((float*)p.hA + rbase + tid * 4, ((const floatx4*)hs[0])[tid]);
        ntst4((float*)(p.hA + BATCHN) + rbase + tid * 4, ((const floatx4*)hs[1])[tid]);
        stats_deposit<4>(bsum, p.gstats, tid, bid);
        dev_barrier(p, 0, tid, bid);
    }

    // ---- layers 1..9 (ping-pong hA/hB) ----
    do_layer<1>(p, p.hA, p.hB, lw2, lB, lG, lT, bsum, red, lsc, lsh, tid, bid);
    do_layer<2>(p, p.hB, p.hA, lw2, lB, lG, lT, bsum, red, lsc, lsh, tid, bid);
    do_layer<3>(p, p.hA, p.hB, lw2, lB, lG, lT, bsum, red, lsc, lsh, tid, bid);
    do_layer<4>(p, p.hB, p.hA, lw2, lB, lG, lT, bsum, red, lsc, lsh, tid, bid);
    do_layer<5>(p, p.hA, p.hB, lw2, lB, lG, lT, bsum, red, lsc, lsh, tid, bid);
    do_layer<6>(p, p.hB, p.hA, lw2, lB, lG, lT, bsum, red, lsc, lsh, tid, bid);
    do_layer<7>(p, p.hA, p.hB, lw2, lB, lG, lT, bsum, red, lsc, lsh, tid, bid);
    do_layer<8>(p, p.hB, p.hA, lw2, lB, lG, lT, bsum, red, lsc, lsh, tid, bid);
    do_layer<9>(p, p.hA, p.hB, lw2, lB, lG, lT, bsum, red, lsc, lsh, tid, bid);

    // ---- layer 10: BN_9+tanh, linear 5->1, sigmoid -> out ----
    {
        constexpr int WO = w2offc(10), BO = boffc(10), GO = boffc(9);
        const float* gsPrev = p.gstats + (size_t)9 * NSLOT * SLOTW;
        if (tid < 10) red[tid] = 0.0f;
        __syncthreads();
        {
            const int f = tid & 63, c = tid >> 6;
            if (f < 10) {
                const int idx = (f < 5) ? f : (24 + (f - 5));
                float v = 0.0f;
#pragma unroll
                for (int q = 0; q < 16; ++q)
                    v += gsPrev[(c * 16 + q) * SLOTW + idx];
                atomicAdd(&red[f], v);
            }
        }
        __syncthreads();
        if (tid < 5) {
            constexpr float inv = 1.0f / (float)BATCHN;
            const float m = red[tid] * inv;
            const float var = fmaxf(red[5 + tid] * inv - m * m, 0.0f);
            const float sc = lG[GO + tid] * rsqrtf(var + 1e-5f);
            lsc[tid] = sc;
            lsh[tid] = lT[GO + tid] - m * sc;
        }
        if (tid == 5) { lsc[5] = 0.0f; lsh[5] = 0.0f; }
        __syncthreads();

        const int ei = bid * NTHR + tid;
        const float lb0 = lB[BO];
        float a[4] = {lb0, lb0, lb0, lb0};
#pragma unroll
        for (int cp = 0; cp < 3; ++cp) {
            const float2 w = lw2[WO + cp];
            const floatx4 pl = ntld4((const float*)(p.hB + (size_t)cp * BATCHN) + (size_t)ei * 4);
            const __half2* h4 = (const __half2*)&pl;
#pragma unroll
            for (int r = 0; r < 4; ++r) {
                const float t0 = fast_tanh(fmaf(__low2float(h4[r]), lsc[2 * cp], lsh[2 * cp]));
                const float t1 = fast_tanh(fmaf(__high2float(h4[r]), lsc[2 * cp + 1], lsh[2 * cp + 1]));
                a[r] = fmaf(w.x, t0, fmaf(w.y, t1, a[r]));
            }
        }
        floatx4 ov;
#pragma unroll
        for (int r = 0; r < 4; ++r) {
            const float e = exp2f(a[r] * -1.4426950408889634f);
            ov[r] = __fdividef(1.0f, 1.0f + e);
        }
        ntst4(p.out + (size_t)ei * 4, ov);
    }
}

// zero gstats + bar + flags each call (ws is not re-poisoned between replays)
__global__ void init_ws(float* __restrict__ gstats, unsigned* __restrict__ bar,
                        unsigned* __restrict__ flags) {
    const int i = threadIdx.x + blockIdx.x * blockDim.x;
    if (i < 10 * NSLOT * SLOTW) gstats[i] = 0.0f;
    if (i < 10 * 8 * BARPAD) { bar[i] = 0u; flags[i] = 0u; }
}

extern "C" void kernel_launch(void* const* d_in, const int* in_sizes, int n_in,
                              void* d_out, int out_size, void* d_ws, size_t ws_size,
                              hipStream_t stream) {
    Params p;
    p.x = (const float*)d_in[0];
    int k = 1;
    for (int l = 0; l < 11; ++l) {
        p.W[l] = (const float*)d_in[k++];
        p.b[l] = (const float*)d_in[k++];
        if (l < 10) {
            p.g[l] = (const float*)d_in[k++];
            p.bt[l] = (const float*)d_in[k++];
        }
    }
    p.out = (float*)d_out;

    // ws layout (bytes):
    //   gstats @ 0      : 10*64*48*4 = 122880
    //   bar    @ 122880 : 10*8*32*4  = 10240
    //   flags  @ 133120 : 10*8*32*4  = 10240
    //   hA     @ 262144 : 5 planes x 4MB
    //   hB     @ 262144+20971520 : 10 planes x 4MB
    char* ws = (char*)d_ws;
    p.gstats = (float*)ws;
    p.bar    = (unsigned*)(ws + 122880);
    p.flags  = (unsigned*)(ws + 133120);
    p.hA     = (__half2*)(ws + 262144);
    p.hB     = (__half2*)(ws + 262144 + 20971520);

    init_ws<<<dim3(120), dim3(256), 0, stream>>>(p.gstats, p.bar, p.flags);
    mlp_fused<<<dim3(NBLK), dim3(NTHR), 0, stream>>>(p);
}